// Round 1
// baseline (179.093 us; speedup 1.0000x reference)
//
#include <hip/hip_runtime.h>

// ---------------- problem constants ----------------
constexpr int   kB     = 1024;
constexpr int   kH     = 28;
constexpr int   kW     = 28;
constexpr int   kCells = kB * kH * kW;   // 802816
constexpr int   kCh    = 30;             // 10 + 20 classes
constexpr float kLCoord = 5.0f, kLObj = 1.0f, kLNoobj = 0.5f;

// IoU of decoded boxes: a = target (cx,cy,sw,sh), b = pred. w = sw^2, h = sh^2.
__device__ __forceinline__ float iou_decoded(
    float pcx, float pcy, float psw, float psh,
    float tcx, float tcy, float tsw, float tsh)
{
    float aw = tsw * tsw, ah = tsh * tsh;
    float a0 = tcx - aw * 0.5f, a1 = tcy - ah * 0.5f;
    float a2 = tcx + aw * 0.5f, a3 = tcy + ah * 0.5f;
    float bw = psw * psw, bh = psh * psh;
    float b0 = pcx - bw * 0.5f, b1 = pcy - bh * 0.5f;
    float b2 = pcx + bw * 0.5f, b3 = pcy + bh * 0.5f;
    float x0 = fmaxf(a0, b0), y0 = fmaxf(a1, b1);
    float x1 = fminf(a2, b2), y1 = fminf(a3, b3);
    float inter  = fmaxf(x1 - x0, 0.0f) * fmaxf(y1 - y0, 0.0f);
    float area_a = (a2 - a0) * (a3 - a1);
    float area_b = (b2 - b0) * (b3 - b1);
    return inter / (area_a + area_b - inter + 1e-10f);
}

// ws layout: [0]=cls_raw [1]=resp_raw [2]=off_raw [3]=neg_raw  (unscaled sums)
__global__ __launch_bounds__(256) void yolo_loss_main(
    const float* __restrict__ pred, const float* __restrict__ meta,
    float* __restrict__ ws)
{
    const int cell = blockIdx.x * blockDim.x + threadIdx.x;  // grid sized exactly

    // ---- load 30+30 floats as aligned float2 (cell stride 120 B = 8B-aligned) ----
    float pv[kCh], mv[kCh];
    {
        const float2* p2 = reinterpret_cast<const float2*>(pred + (size_t)cell * kCh);
        const float2* m2 = reinterpret_cast<const float2*>(meta + (size_t)cell * kCh);
        #pragma unroll
        for (int i = 0; i < kCh / 2; ++i) {
            float2 a = p2[i]; pv[2 * i] = a.x; pv[2 * i + 1] = a.y;
            float2 b = m2[i]; mv[2 * i] = b.x; mv[2 * i + 1] = b.y;
        }
    }

    const float t_resp0 = mv[4], t_resp1 = mv[9];
    const float pos = (t_resp0 + t_resp1 > 0.9f) ? 1.0f : 0.0f;

    // ---- class loss ----
    float cls_acc = 0.0f;
    #pragma unroll
    for (int c = 0; c < 20; ++c) {
        float d = pv[10 + c] - mv[10 + c];
        cls_acc += d * d;
    }
    float l_cls = pos * cls_acc;

    // ---- IoU for both boxes; best = argmax (first-max tie-break => strict >) ----
    float iou0 = iou_decoded(pv[0], pv[1], pv[2], pv[3], mv[0], mv[1], mv[2], mv[3]);
    float iou1 = iou_decoded(pv[5], pv[6], pv[7], pv[8], mv[5], mv[6], mv[7], mv[8]);
    bool  best1 = (iou1 > iou0);

    float iou_b    = best1 ? iou1  : iou0;
    float p_resp_b = best1 ? pv[9] : pv[4];
    float dr = p_resp_b - iou_b;
    float l_resp = pos * dr * dr;

    float off_acc = 0.0f;
    #pragma unroll
    for (int k = 0; k < 4; ++k) {
        float pb = best1 ? pv[5 + k] : pv[k];
        float tb = best1 ? mv[5 + k] : mv[k];
        float d  = pb - tb;
        off_acc += d * d;
    }
    float l_off = pos * off_acc;

    // ---- noobj response (both boxes, mask t_resp < 1) ----
    float n0 = (t_resp0 < 1.0f) ? 1.0f : 0.0f;
    float n1 = (t_resp1 < 1.0f) ? 1.0f : 0.0f;
    float d0 = pv[4] - t_resp0, d1 = pv[9] - t_resp1;
    float l_neg = n0 * d0 * d0 + n1 * d1 * d1;

    // ---- hierarchical reduction: wave shuffle -> LDS -> global atomics ----
    #pragma unroll
    for (int off = 32; off > 0; off >>= 1) {
        l_cls  += __shfl_down(l_cls,  off);
        l_resp += __shfl_down(l_resp, off);
        l_off  += __shfl_down(l_off,  off);
        l_neg  += __shfl_down(l_neg,  off);
    }

    __shared__ float red[4][4];  // [metric][wave]
    const int lane = threadIdx.x & 63;
    const int wid  = threadIdx.x >> 6;
    if (lane == 0) {
        red[0][wid] = l_cls;
        red[1][wid] = l_resp;
        red[2][wid] = l_off;
        red[3][wid] = l_neg;
    }
    __syncthreads();
    if (threadIdx.x == 0) {
        float s0 = red[0][0] + red[0][1] + red[0][2] + red[0][3];
        float s1 = red[1][0] + red[1][1] + red[1][2] + red[1][3];
        float s2 = red[2][0] + red[2][1] + red[2][2] + red[2][3];
        float s3 = red[3][0] + red[3][1] + red[3][2] + red[3][3];
        atomicAdd(&ws[0], s0);
        atomicAdd(&ws[1], s1);
        atomicAdd(&ws[2], s2);
        atomicAdd(&ws[3], s3);
    }
}

// out: (loss_sum, loss_pos_response, loss_neg_response, loss_pos_cls, loss_pos_offset)
__global__ void yolo_loss_finalize(const float* __restrict__ ws, float* __restrict__ out)
{
    float inv_b  = 1.0f / (float)kB;
    float l_cls  = ws[0] * inv_b;
    float l_resp = ws[1] * inv_b * kLObj;
    float l_off  = ws[2] * inv_b * kLCoord;
    float l_neg  = ws[3] * inv_b * kLNoobj;
    out[0] = l_neg + l_resp + l_off + l_cls;  // reference addition order
    out[1] = l_resp;
    out[2] = l_neg;
    out[3] = l_cls;
    out[4] = l_off;
}

extern "C" void kernel_launch(void* const* d_in, const int* in_sizes, int n_in,
                              void* d_out, int out_size, void* d_ws, size_t ws_size,
                              hipStream_t stream) {
    const float* pred = (const float*)d_in[0];
    const float* meta = (const float*)d_in[1];
    float* out = (float*)d_out;
    float* ws  = (float*)d_ws;

    // zero the 4 accumulators (ws is poisoned, not re-zeroed between replays)
    hipMemsetAsync(ws, 0, 4 * sizeof(float), stream);

    const int threads = 256;
    const int blocks  = kCells / threads;  // 802816 / 256 = 3136 exact
    yolo_loss_main<<<blocks, threads, 0, stream>>>(pred, meta, ws);
    yolo_loss_finalize<<<1, 1, 0, stream>>>(ws, out);
}

// Round 2
// 176.510 us; speedup vs baseline: 1.0146x; 1.0146x over previous
//
#include <hip/hip_runtime.h>

// ---------------- problem constants ----------------
constexpr int   kB     = 1024;
constexpr int   kH     = 28;
constexpr int   kW     = 28;
constexpr int   kCells = kB * kH * kW;   // 802816
constexpr int   kCh    = 30;             // 10 + 20 classes
constexpr int   kPad   = 31;             // LDS row stride (conflict-free: gcd(31,32)=1)
constexpr int   kCPB   = 256;            // cells per block
constexpr float kLCoord = 5.0f, kLObj = 1.0f, kLNoobj = 0.5f;

__device__ __forceinline__ float iou_decoded(
    float pcx, float pcy, float psw, float psh,
    float tcx, float tcy, float tsw, float tsh)
{
    float aw = tsw * tsw, ah = tsh * tsh;
    float a0 = tcx - aw * 0.5f, a1 = tcy - ah * 0.5f;
    float a2 = tcx + aw * 0.5f, a3 = tcy + ah * 0.5f;
    float bw = psw * psw, bh = psh * psh;
    float b0 = pcx - bw * 0.5f, b1 = pcy - bh * 0.5f;
    float b2 = pcx + bw * 0.5f, b3 = pcy + bh * 0.5f;
    float x0 = fmaxf(a0, b0), y0 = fmaxf(a1, b1);
    float x1 = fminf(a2, b2), y1 = fminf(a3, b3);
    float inter  = fmaxf(x1 - x0, 0.0f) * fmaxf(y1 - y0, 0.0f);
    float area_a = (a2 - a0) * (a3 - a1);
    float area_b = (b2 - b0) * (b3 - b1);
    return inter / (area_a + area_b - inter + 1e-10f);
}

// ws layout: [0]=cls_raw [1]=resp_raw [2]=off_raw [3]=neg_raw  (unscaled sums)
__global__ __launch_bounds__(256) void yolo_loss_main(
    const float* __restrict__ pred, const float* __restrict__ meta,
    float* __restrict__ ws)
{
    __shared__ float sp[kCPB * kPad];   // 31744 B
    __shared__ float sm[kCPB * kPad];   // 31744 B  (total 62 KB)

    const int t = threadIdx.x;

    // ---- coalesced global -> LDS staging ----
    // Block span: 256 cells * 30 floats = 7680 floats = 3840 float2 per array.
    // Thread t loads float2 index j = t + 256*i (i=0..14): lane-adjacent => coalesced.
    // Block base float offset = blockIdx.x*256*30 (8B-aligned for float2: 30720B multiple).
    {
        const size_t base = (size_t)blockIdx.x * kCPB * kCh;
        const float2* p2 = reinterpret_cast<const float2*>(pred + base);
        const float2* m2 = reinterpret_cast<const float2*>(meta + base);
        #pragma unroll
        for (int i = 0; i < (kCPB * kCh / 2) / 256; ++i) {   // 15 iters
            int j = t + 256 * i;        // float2 index in block span
            float2 a = p2[j];
            float2 b = m2[j];
            int cell = j / 15;          // = (2j)/30
            int ch   = 2 * j - cell * kCh;  // even, 0..28 (pair never straddles a cell)
            int addr = cell * kPad + ch;
            sp[addr] = a.x; sp[addr + 1] = a.y;
            sm[addr] = b.x; sm[addr + 1] = b.y;
        }
    }
    __syncthreads();

    // ---- per-thread gather from LDS (stride 31 => bank (k-t)%32, conflict-free) ----
    float pv[kCh], mv[kCh];
    #pragma unroll
    for (int k = 0; k < kCh; ++k) {
        pv[k] = sp[t * kPad + k];
        mv[k] = sm[t * kPad + k];
    }

    const float t_resp0 = mv[4], t_resp1 = mv[9];
    const float pos = (t_resp0 + t_resp1 > 0.9f) ? 1.0f : 0.0f;

    // ---- class loss ----
    float cls_acc = 0.0f;
    #pragma unroll
    for (int c = 0; c < 20; ++c) {
        float d = pv[10 + c] - mv[10 + c];
        cls_acc += d * d;
    }
    float l_cls = pos * cls_acc;

    // ---- IoU for both boxes; best = argmax (first-max tie-break => strict >) ----
    float iou0 = iou_decoded(pv[0], pv[1], pv[2], pv[3], mv[0], mv[1], mv[2], mv[3]);
    float iou1 = iou_decoded(pv[5], pv[6], pv[7], pv[8], mv[5], mv[6], mv[7], mv[8]);
    bool  best1 = (iou1 > iou0);

    float iou_b    = best1 ? iou1  : iou0;
    float p_resp_b = best1 ? pv[9] : pv[4];
    float dr = p_resp_b - iou_b;
    float l_resp = pos * dr * dr;

    float off_acc = 0.0f;
    #pragma unroll
    for (int k = 0; k < 4; ++k) {
        float pb = best1 ? pv[5 + k] : pv[k];
        float tb = best1 ? mv[5 + k] : mv[k];
        float d  = pb - tb;
        off_acc += d * d;
    }
    float l_off = pos * off_acc;

    // ---- noobj response ----
    float n0 = (t_resp0 < 1.0f) ? 1.0f : 0.0f;
    float n1 = (t_resp1 < 1.0f) ? 1.0f : 0.0f;
    float d0 = pv[4] - t_resp0, d1 = pv[9] - t_resp1;
    float l_neg = n0 * d0 * d0 + n1 * d1 * d1;

    // ---- hierarchical reduction: wave shuffle -> LDS -> global atomics ----
    #pragma unroll
    for (int off = 32; off > 0; off >>= 1) {
        l_cls  += __shfl_down(l_cls,  off);
        l_resp += __shfl_down(l_resp, off);
        l_off  += __shfl_down(l_off,  off);
        l_neg  += __shfl_down(l_neg,  off);
    }

    __shared__ float red[4][4];  // [metric][wave]
    const int lane = t & 63;
    const int wid  = t >> 6;
    if (lane == 0) {
        red[0][wid] = l_cls;
        red[1][wid] = l_resp;
        red[2][wid] = l_off;
        red[3][wid] = l_neg;
    }
    __syncthreads();
    if (t == 0) {
        atomicAdd(&ws[0], red[0][0] + red[0][1] + red[0][2] + red[0][3]);
        atomicAdd(&ws[1], red[1][0] + red[1][1] + red[1][2] + red[1][3]);
        atomicAdd(&ws[2], red[2][0] + red[2][1] + red[2][2] + red[2][3]);
        atomicAdd(&ws[3], red[3][0] + red[3][1] + red[3][2] + red[3][3]);
    }
}

// out: (loss_sum, loss_pos_response, loss_neg_response, loss_pos_cls, loss_pos_offset)
__global__ void yolo_loss_finalize(const float* __restrict__ ws, float* __restrict__ out)
{
    float inv_b  = 1.0f / (float)kB;
    float l_cls  = ws[0] * inv_b;
    float l_resp = ws[1] * inv_b * kLObj;
    float l_off  = ws[2] * inv_b * kLCoord;
    float l_neg  = ws[3] * inv_b * kLNoobj;
    out[0] = l_neg + l_resp + l_off + l_cls;  // reference addition order
    out[1] = l_resp;
    out[2] = l_neg;
    out[3] = l_cls;
    out[4] = l_off;
}

extern "C" void kernel_launch(void* const* d_in, const int* in_sizes, int n_in,
                              void* d_out, int out_size, void* d_ws, size_t ws_size,
                              hipStream_t stream) {
    const float* pred = (const float*)d_in[0];
    const float* meta = (const float*)d_in[1];
    float* out = (float*)d_out;
    float* ws  = (float*)d_ws;

    // zero the 4 accumulators (ws is poisoned, not re-zeroed between replays)
    hipMemsetAsync(ws, 0, 4 * sizeof(float), stream);

    const int threads = 256;
    const int blocks  = kCells / kCPB;  // 3136 exact
    yolo_loss_main<<<blocks, threads, 0, stream>>>(pred, meta, ws);
    yolo_loss_finalize<<<1, 1, 0, stream>>>(ws, out);
}

// Round 3
// 47.507 us; speedup vs baseline: 3.7698x; 3.7154x over previous
//
#include <hip/hip_runtime.h>

// ---------------- problem constants ----------------
constexpr int   kB     = 1024;
constexpr int   kH     = 28;
constexpr int   kW     = 28;
constexpr int   kCells = kB * kH * kW;   // 802816
constexpr int   kCh    = 30;             // 10 + 20 classes
constexpr int   kPad   = 31;             // LDS row stride (conflict-free: gcd(31,32)=1)
constexpr int   kCPB   = 256;            // cells per block
constexpr int   kBlocks = kCells / kCPB; // 3136
constexpr float kLCoord = 5.0f, kLObj = 1.0f, kLNoobj = 0.5f;

__device__ __forceinline__ float iou_decoded(
    float pcx, float pcy, float psw, float psh,
    float tcx, float tcy, float tsw, float tsh)
{
    float aw = tsw * tsw, ah = tsh * tsh;
    float a0 = tcx - aw * 0.5f, a1 = tcy - ah * 0.5f;
    float a2 = tcx + aw * 0.5f, a3 = tcy + ah * 0.5f;
    float bw = psw * psw, bh = psh * psh;
    float b0 = pcx - bw * 0.5f, b1 = pcy - bh * 0.5f;
    float b2 = pcx + bw * 0.5f, b3 = pcy + bh * 0.5f;
    float x0 = fmaxf(a0, b0), y0 = fmaxf(a1, b1);
    float x1 = fminf(a2, b2), y1 = fminf(a3, b3);
    float inter  = fmaxf(x1 - x0, 0.0f) * fmaxf(y1 - y0, 0.0f);
    float area_a = (a2 - a0) * (a3 - a1);
    float area_b = (b2 - b0) * (b3 - b1);
    return inter / (area_a + area_b - inter + 1e-10f);
}

// ws layout: ws[m*kBlocks + b] = block b's partial for metric m
// m: 0=cls 1=resp 2=off 3=neg  (unscaled sums)
__global__ __launch_bounds__(256) void yolo_loss_main(
    const float* __restrict__ pred, const float* __restrict__ meta,
    float* __restrict__ ws)
{
    __shared__ float sp[kCPB * kPad];   // 31744 B
    __shared__ float sm[kCPB * kPad];   // 31744 B  (total 62 KB)

    const int t = threadIdx.x;

    // ---- coalesced global -> LDS staging ----
    {
        const size_t base = (size_t)blockIdx.x * kCPB * kCh;
        const float2* p2 = reinterpret_cast<const float2*>(pred + base);
        const float2* m2 = reinterpret_cast<const float2*>(meta + base);
        #pragma unroll
        for (int i = 0; i < (kCPB * kCh / 2) / 256; ++i) {   // 15 iters
            int j = t + 256 * i;            // float2 index in block span
            float2 a = p2[j];
            float2 b = m2[j];
            int cell = j / 15;              // = (2j)/30
            int ch   = 2 * j - cell * kCh;  // even, 0..28 (pair never straddles a cell)
            int addr = cell * kPad + ch;
            sp[addr] = a.x; sp[addr + 1] = a.y;
            sm[addr] = b.x; sm[addr + 1] = b.y;
        }
    }
    __syncthreads();

    // ---- per-thread gather from LDS (stride 31 => bank (k-t)%32, conflict-free) ----
    float pv[kCh], mv[kCh];
    #pragma unroll
    for (int k = 0; k < kCh; ++k) {
        pv[k] = sp[t * kPad + k];
        mv[k] = sm[t * kPad + k];
    }

    const float t_resp0 = mv[4], t_resp1 = mv[9];
    const float pos = (t_resp0 + t_resp1 > 0.9f) ? 1.0f : 0.0f;

    // ---- class loss ----
    float cls_acc = 0.0f;
    #pragma unroll
    for (int c = 0; c < 20; ++c) {
        float d = pv[10 + c] - mv[10 + c];
        cls_acc += d * d;
    }
    float l_cls = pos * cls_acc;

    // ---- IoU for both boxes; best = argmax (first-max tie-break => strict >) ----
    float iou0 = iou_decoded(pv[0], pv[1], pv[2], pv[3], mv[0], mv[1], mv[2], mv[3]);
    float iou1 = iou_decoded(pv[5], pv[6], pv[7], pv[8], mv[5], mv[6], mv[7], mv[8]);
    bool  best1 = (iou1 > iou0);

    float iou_b    = best1 ? iou1  : iou0;
    float p_resp_b = best1 ? pv[9] : pv[4];
    float dr = p_resp_b - iou_b;
    float l_resp = pos * dr * dr;

    float off_acc = 0.0f;
    #pragma unroll
    for (int k = 0; k < 4; ++k) {
        float pb = best1 ? pv[5 + k] : pv[k];
        float tb = best1 ? mv[5 + k] : mv[k];
        float d  = pb - tb;
        off_acc += d * d;
    }
    float l_off = pos * off_acc;

    // ---- noobj response ----
    float n0 = (t_resp0 < 1.0f) ? 1.0f : 0.0f;
    float n1 = (t_resp1 < 1.0f) ? 1.0f : 0.0f;
    float d0 = pv[4] - t_resp0, d1 = pv[9] - t_resp1;
    float l_neg = n0 * d0 * d0 + n1 * d1 * d1;

    // ---- hierarchical reduction: wave shuffle -> LDS -> per-block private stores ----
    #pragma unroll
    for (int off = 32; off > 0; off >>= 1) {
        l_cls  += __shfl_down(l_cls,  off);
        l_resp += __shfl_down(l_resp, off);
        l_off  += __shfl_down(l_off,  off);
        l_neg  += __shfl_down(l_neg,  off);
    }

    __shared__ float red[4][4];  // [metric][wave]
    const int lane = t & 63;
    const int wid  = t >> 6;
    if (lane == 0) {
        red[0][wid] = l_cls;
        red[1][wid] = l_resp;
        red[2][wid] = l_off;
        red[3][wid] = l_neg;
    }
    __syncthreads();
    if (t == 0) {
        const int b = blockIdx.x;
        ws[0 * kBlocks + b] = red[0][0] + red[0][1] + red[0][2] + red[0][3];
        ws[1 * kBlocks + b] = red[1][0] + red[1][1] + red[1][2] + red[1][3];
        ws[2 * kBlocks + b] = red[2][0] + red[2][1] + red[2][2] + red[2][3];
        ws[3 * kBlocks + b] = red[3][0] + red[3][1] + red[3][2] + red[3][3];
    }
}

// Single-block deterministic reduce of the 4 x 3136 partials + finalize.
// out: (loss_sum, loss_pos_response, loss_neg_response, loss_pos_cls, loss_pos_offset)
__global__ __launch_bounds__(256) void yolo_loss_reduce(
    const float* __restrict__ ws, float* __restrict__ out)
{
    const int t = threadIdx.x;
    float acc[4] = {0.0f, 0.0f, 0.0f, 0.0f};
    #pragma unroll
    for (int m = 0; m < 4; ++m) {
        for (int i = t; i < kBlocks; i += 256) {   // coalesced
            acc[m] += ws[m * kBlocks + i];
        }
    }
    #pragma unroll
    for (int off = 32; off > 0; off >>= 1) {
        acc[0] += __shfl_down(acc[0], off);
        acc[1] += __shfl_down(acc[1], off);
        acc[2] += __shfl_down(acc[2], off);
        acc[3] += __shfl_down(acc[3], off);
    }
    __shared__ float red[4][4];
    const int lane = t & 63;
    const int wid  = t >> 6;
    if (lane == 0) {
        red[0][wid] = acc[0];
        red[1][wid] = acc[1];
        red[2][wid] = acc[2];
        red[3][wid] = acc[3];
    }
    __syncthreads();
    if (t == 0) {
        float inv_b  = 1.0f / (float)kB;
        float s_cls  = (red[0][0] + red[0][1] + red[0][2] + red[0][3]) * inv_b;
        float s_resp = (red[1][0] + red[1][1] + red[1][2] + red[1][3]) * inv_b * kLObj;
        float s_off  = (red[2][0] + red[2][1] + red[2][2] + red[2][3]) * inv_b * kLCoord;
        float s_neg  = (red[3][0] + red[3][1] + red[3][2] + red[3][3]) * inv_b * kLNoobj;
        out[0] = s_neg + s_resp + s_off + s_cls;  // reference addition order
        out[1] = s_resp;
        out[2] = s_neg;
        out[3] = s_cls;
        out[4] = s_off;
    }
}

extern "C" void kernel_launch(void* const* d_in, const int* in_sizes, int n_in,
                              void* d_out, int out_size, void* d_ws, size_t ws_size,
                              hipStream_t stream) {
    const float* pred = (const float*)d_in[0];
    const float* meta = (const float*)d_in[1];
    float* out = (float*)d_out;
    float* ws  = (float*)d_ws;

    // No ws zeroing needed: every ws slot [0, 4*kBlocks) is written by main.
    yolo_loss_main<<<kBlocks, 256, 0, stream>>>(pred, meta, ws);
    yolo_loss_reduce<<<1, 256, 0, stream>>>(ws, out);
}

// Round 4
// 39.867 us; speedup vs baseline: 4.4922x; 1.1916x over previous
//
#include <hip/hip_runtime.h>

// ---------------- problem constants ----------------
constexpr int   kB      = 1024;
constexpr int   kH      = 28;
constexpr int   kW      = 28;
constexpr int   kCells  = kB * kH * kW;    // 802816
constexpr int   kCh     = 30;              // 10 + 20 classes
constexpr int   kCPB    = 256;             // cells per block (1 per thread)
constexpr int   kBlocks = kCells / kCPB;   // 3136
constexpr float kLCoord = 5.0f, kLObj = 1.0f, kLNoobj = 0.5f;

__device__ __forceinline__ float iou_decoded(
    float pcx, float pcy, float psw, float psh,
    float tcx, float tcy, float tsw, float tsh)
{
    float aw = tsw * tsw, ah = tsh * tsh;
    float a0 = tcx - aw * 0.5f, a1 = tcy - ah * 0.5f;
    float a2 = tcx + aw * 0.5f, a3 = tcy + ah * 0.5f;
    float bw = psw * psw, bh = psh * psh;
    float b0 = pcx - bw * 0.5f, b1 = pcy - bh * 0.5f;
    float b2 = pcx + bw * 0.5f, b3 = pcy + bh * 0.5f;
    float x0 = fmaxf(a0, b0), y0 = fmaxf(a1, b1);
    float x1 = fminf(a2, b2), y1 = fminf(a3, b3);
    float inter  = fmaxf(x1 - x0, 0.0f) * fmaxf(y1 - y0, 0.0f);
    float area_a = (a2 - a0) * (a3 - a1);
    float area_b = (b2 - b0) * (b3 - b1);
    return inter / (area_a + area_b - inter + 1e-10f);
}

// ws layout: ws[m*kBlocks + b] = block b's partial for metric m
// m: 0=cls 1=resp 2=off 3=neg  (unscaled sums)
__global__ __launch_bounds__(256) void yolo_loss_main(
    const float* __restrict__ pred, const float* __restrict__ meta,
    float* __restrict__ ws)
{
    const int t    = threadIdx.x;
    const int cell = blockIdx.x * kCPB + t;

    const float* pc = pred + (size_t)cell * kCh;
    const float* mc = meta + (size_t)cell * kCh;

    // Cheap classification loads: meta ch4==ch9==resp by construction.
    float resp = mc[4];
    float p4   = pc[4];
    float p9   = pc[9];

    float l_cls = 0.0f, l_resp = 0.0f, l_off = 0.0f, l_neg = 0.0f;

    if (resp + resp > 0.9f) {
        // ---- positive cell (~2% of lanes): full faithful computation ----
        float pv[kCh], mv[kCh];
        const float2* p2 = reinterpret_cast<const float2*>(pc);
        const float2* m2 = reinterpret_cast<const float2*>(mc);
        #pragma unroll
        for (int i = 0; i < kCh / 2; ++i) {
            float2 a = p2[i]; pv[2 * i] = a.x; pv[2 * i + 1] = a.y;
            float2 b = m2[i]; mv[2 * i] = b.x; mv[2 * i + 1] = b.y;
        }

        const float pos = (mv[4] + mv[9] > 0.9f) ? 1.0f : 0.0f;

        float cls_acc = 0.0f;
        #pragma unroll
        for (int c = 0; c < 20; ++c) {
            float d = pv[10 + c] - mv[10 + c];
            cls_acc += d * d;
        }
        l_cls = pos * cls_acc;

        float iou0 = iou_decoded(pv[0], pv[1], pv[2], pv[3], mv[0], mv[1], mv[2], mv[3]);
        float iou1 = iou_decoded(pv[5], pv[6], pv[7], pv[8], mv[5], mv[6], mv[7], mv[8]);
        bool  best1 = (iou1 > iou0);

        float iou_b    = best1 ? iou1  : iou0;
        float p_resp_b = best1 ? pv[9] : pv[4];
        float dr = p_resp_b - iou_b;
        l_resp = pos * dr * dr;

        float off_acc = 0.0f;
        #pragma unroll
        for (int k = 0; k < 4; ++k) {
            float pb = best1 ? pv[5 + k] : pv[k];
            float tb = best1 ? mv[5 + k] : mv[k];
            float d  = pb - tb;
            off_acc += d * d;
        }
        l_off = pos * off_acc;

        float n0 = (mv[4] < 1.0f) ? 1.0f : 0.0f;
        float n1 = (mv[9] < 1.0f) ? 1.0f : 0.0f;
        float d0 = pv[4] - mv[4], d1 = pv[9] - mv[9];
        l_neg = n0 * d0 * d0 + n1 * d1 * d1;
    } else {
        // ---- negative cell: boxes/cls in meta are zero, pos==0.
        // Only the noobj response term survives (mask t_resp < 1).
        float n  = (resp < 1.0f) ? 1.0f : 0.0f;
        float d0 = p4 - resp, d1 = p9 - resp;
        l_neg = n * (d0 * d0 + d1 * d1);
    }

    // ---- hierarchical reduction: wave shuffle -> LDS -> per-block stores ----
    #pragma unroll
    for (int off = 32; off > 0; off >>= 1) {
        l_cls  += __shfl_down(l_cls,  off);
        l_resp += __shfl_down(l_resp, off);
        l_off  += __shfl_down(l_off,  off);
        l_neg  += __shfl_down(l_neg,  off);
    }

    __shared__ float red[4][4];  // [metric][wave]
    const int lane = t & 63;
    const int wid  = t >> 6;
    if (lane == 0) {
        red[0][wid] = l_cls;
        red[1][wid] = l_resp;
        red[2][wid] = l_off;
        red[3][wid] = l_neg;
    }
    __syncthreads();
    if (t == 0) {
        const int b = blockIdx.x;
        ws[0 * kBlocks + b] = red[0][0] + red[0][1] + red[0][2] + red[0][3];
        ws[1 * kBlocks + b] = red[1][0] + red[1][1] + red[1][2] + red[1][3];
        ws[2 * kBlocks + b] = red[2][0] + red[2][1] + red[2][2] + red[2][3];
        ws[3 * kBlocks + b] = red[3][0] + red[3][1] + red[3][2] + red[3][3];
    }
}

// Single-block deterministic reduce of the 4 x 3136 partials + finalize.
// out: (loss_sum, loss_pos_response, loss_neg_response, loss_pos_cls, loss_pos_offset)
__global__ __launch_bounds__(1024) void yolo_loss_reduce(
    const float* __restrict__ ws, float* __restrict__ out)
{
    const int t = threadIdx.x;
    float acc[4] = {0.0f, 0.0f, 0.0f, 0.0f};
    #pragma unroll
    for (int m = 0; m < 4; ++m) {
        for (int i = t; i < kBlocks; i += 1024) {   // coalesced
            acc[m] += ws[m * kBlocks + i];
        }
    }
    #pragma unroll
    for (int off = 32; off > 0; off >>= 1) {
        acc[0] += __shfl_down(acc[0], off);
        acc[1] += __shfl_down(acc[1], off);
        acc[2] += __shfl_down(acc[2], off);
        acc[3] += __shfl_down(acc[3], off);
    }
    __shared__ float red[4][16];
    const int lane = t & 63;
    const int wid  = t >> 6;
    if (lane == 0) {
        red[0][wid] = acc[0];
        red[1][wid] = acc[1];
        red[2][wid] = acc[2];
        red[3][wid] = acc[3];
    }
    __syncthreads();
    if (t == 0) {
        float s[4];
        #pragma unroll
        for (int m = 0; m < 4; ++m) {
            float v = 0.0f;
            #pragma unroll
            for (int w = 0; w < 16; ++w) v += red[m][w];
            s[m] = v;
        }
        float inv_b  = 1.0f / (float)kB;
        float s_cls  = s[0] * inv_b;
        float s_resp = s[1] * inv_b * kLObj;
        float s_off  = s[2] * inv_b * kLCoord;
        float s_neg  = s[3] * inv_b * kLNoobj;
        out[0] = s_neg + s_resp + s_off + s_cls;  // reference addition order
        out[1] = s_resp;
        out[2] = s_neg;
        out[3] = s_cls;
        out[4] = s_off;
    }
}

extern "C" void kernel_launch(void* const* d_in, const int* in_sizes, int n_in,
                              void* d_out, int out_size, void* d_ws, size_t ws_size,
                              hipStream_t stream) {
    const float* pred = (const float*)d_in[0];
    const float* meta = (const float*)d_in[1];
    float* out = (float*)d_out;
    float* ws  = (float*)d_ws;

    // No ws zeroing needed: every ws slot [0, 4*kBlocks) is written by main.
    yolo_loss_main<<<kBlocks, kCPB, 0, stream>>>(pred, meta, ws);
    yolo_loss_reduce<<<1, 1024, 0, stream>>>(ws, out);
}